// Round 5
// baseline (1661.203 us; speedup 1.0000x reference)
//
#include <hip/hip_runtime.h>

typedef float f32x4  __attribute__((ext_vector_type(4)));
typedef float f32x16 __attribute__((ext_vector_type(16)));
typedef int   i32x4  __attribute__((ext_vector_type(4)));
typedef int   i32x8  __attribute__((ext_vector_type(8)));

#define T_DIM 8192
#define H_DIM 4096
#define SC1 0x7f7f7f7f   // e8m0 scale = 127 -> 2^0 = 1.0 in all 4 bytes

__device__ __forceinline__ unsigned int pack_fp8x4(float a, float b, float c, float d) {
    int v = __builtin_amdgcn_cvt_pk_fp8_f32(a, b, 0, false);
    v = __builtin_amdgcn_cvt_pk_fp8_f32(c, d, v, true);
    return (unsigned int)v;
}

// ---------------------------------------------------------------------------
// Global fp8 layout: PLAIN row-major [row][k] for both qx and wqT.
// (mfma_scale 32x32x64 frag = 32 CONTIGUOUS k-bytes per lane: lane l holds
// row l&31, k = (l>>5)*32 + [0..31].)  Staging applies XOR slot swizzle
// slot' = slot ^ ((row>>1)&3) on the GLOBAL source addr (LDS stays linear for
// global_load_lds); ds_read applies the same XOR -> uniform 8 lanes per
// (parity,slot) bank-group = conflict-free optimum for b128.
// ---------------------------------------------------------------------------

// w[l][k][n] f32  ->  wqT[l][n][k] fp8(e4m3), plain layout
__global__ __launch_bounds__(256) void wquant_kernel(
    const float* __restrict__ w, unsigned char* __restrict__ wqT)
{
    const int l  = blockIdx.z;
    const int n0 = blockIdx.x * 64;
    const int k0 = blockIdx.y * 64;
    const int tid = threadIdx.x;
    __shared__ unsigned char tile[64][68];   // [k][n]
    const float* wl = w + (size_t)l * H_DIM * H_DIM;
#pragma unroll
    for (int p = 0; p < 4; ++p) {
        int r = p * 16 + (tid >> 4);         // k within tile
        int c = (tid & 15) * 4;              // n within tile
        f32x4 v = *(const f32x4*)(wl + (size_t)(k0 + r) * H_DIM + n0 + c);
        *(unsigned int*)&tile[r][c] = pack_fp8x4(v[0], v[1], v[2], v[3]);
    }
    __syncthreads();
    const int nl = tid >> 2;                 // n within tile (output row)
    const int g  = tid & 3;                  // 16B chunk within 64B
    unsigned int words[4];
#pragma unroll
    for (int wi = 0; wi < 4; ++wi) {
        unsigned int a = 0;
#pragma unroll
        for (int b = 0; b < 4; ++b)
            a |= (unsigned int)tile[g * 16 + wi * 4 + b][nl] << (8 * b);
        words[wi] = a;
    }
    unsigned char* op = wqT + ((size_t)l * H_DIM + n0 + nl) * H_DIM + k0 + g * 16;
    uint4 ov; ov.x = words[0]; ov.y = words[1]; ov.z = words[2]; ov.w = words[3];
    *(uint4*)op = ov;
}

// ---------------- row-wise RMSNorm (+relu) (+quant) ----------------
// MODE 0: x = relu(in); resid_out = x; qx = fp8 (plain layout)
// MODE 1: x = in;                      qx = fp8 (plain layout)
// MODE 2: x = in;                      out = f32 rms(x)*g
template <int MODE>
__global__ __launch_bounds__(256) void row_kernel(
    const float* __restrict__ in,
    float* __restrict__ resid_out,
    void* __restrict__ out,
    const float* __restrict__ g,
    const float* __restrict__ scale_p)
{
    const int row = blockIdx.x;
    const int tid = threadIdx.x;
    const float* rin = in + (size_t)row * H_DIM;
    float x[16];
    float ss = 0.0f;
#pragma unroll
    for (int j = 0; j < 4; ++j) {
        const int base = (j * 256 + tid) * 4;
        f32x4 v = *(const f32x4*)(rin + base);
        f32x4 rv;
#pragma unroll
        for (int i = 0; i < 4; ++i) {
            float t = v[i];
            if (MODE == 0) t = fmaxf(t, 0.0f);
            x[j * 4 + i] = t;
            rv[i] = t;
            ss += t * t;
        }
        if (MODE == 0)
            *(f32x4*)(resid_out + (size_t)row * H_DIM + base) = rv;
    }
#pragma unroll
    for (int off = 32; off > 0; off >>= 1)
        ss += __shfl_down(ss, off, 64);
    __shared__ float red[4];
    if ((tid & 63) == 0) red[tid >> 6] = ss;
    __syncthreads();
    const float var  = (red[0] + red[1] + red[2] + red[3]) * (1.0f / (float)H_DIM);
    const float rinv = 1.0f / sqrtf(var + 1e-6f);

    if (MODE == 2) {
        float* ro = (float*)out + (size_t)row * H_DIM;
#pragma unroll
        for (int j = 0; j < 4; ++j) {
            const int base = (j * 256 + tid) * 4;
            f32x4 gv = *(const f32x4*)(g + base);
            f32x4 ov;
#pragma unroll
            for (int i = 0; i < 4; ++i) ov[i] = (x[j * 4 + i] * rinv) * gv[i];
            *(f32x4*)(ro + base) = ov;
        }
    } else {
        const float s = scale_p[0];
        unsigned int* qo = (unsigned int*)out + (size_t)row * (H_DIM / 4);
#pragma unroll
        for (int j = 0; j < 4; ++j) {
            const int base = (j * 256 + tid) * 4;
            f32x4 gv = *(const f32x4*)(g + base);
            float q[4];
#pragma unroll
            for (int i = 0; i < 4; ++i) {
                float y = (x[j * 4 + i] * rinv) * gv[i];
                y = y / s;
                q[i] = fminf(fmaxf(y, -448.0f), 448.0f);
            }
            qo[j * 256 + tid] = pack_fp8x4(q[0], q[1], q[2], q[3]);
        }
    }
}

// ------- MX-fp8 GEMM, 256x256 tile, BK=64, 1 barrier/tile, 3-deep pipeline ---
// Intra-tile interleave: MFMA pair (tile t) / ds_read pair (tile t+1)
// alternating, pinned with sched_barrier(0). Per-register WAR keeps order:
// fa[m] is dead after MM2(m); fb dead after MM2(3).
__device__ __forceinline__ void stage_half(const unsigned char* gsrc, unsigned char* ldsdst) {
    __builtin_amdgcn_global_load_lds(
        (const __attribute__((address_space(1))) unsigned int*)gsrc,
        (__attribute__((address_space(3))) unsigned int*)ldsdst, 16, 0, 0);
}

#define VM4 asm volatile("s_waitcnt vmcnt(4)" ::: "memory")
#define VM0 asm volatile("s_waitcnt vmcnt(0)" ::: "memory")
#define LGKM0 do { asm volatile("s_waitcnt lgkmcnt(0)" ::: "memory"); \
                   __builtin_amdgcn_sched_barrier(0); } while (0)

#define MM2(m) do {                                                             \
    __builtin_amdgcn_s_setprio(1);                                              \
    acc[m][0] = __builtin_amdgcn_mfma_scale_f32_32x32x64_f8f6f4(                \
        fa[m], fb[0], acc[m][0], 0, 0, 0, SC1, 0, SC1);                         \
    acc[m][1] = __builtin_amdgcn_mfma_scale_f32_32x32x64_f8f6f4(                \
        fa[m], fb[1], acc[m][1], 0, 0, 0, SC1, 0, SC1);                         \
    __builtin_amdgcn_s_setprio(0);                                              \
    __builtin_amdgcn_sched_barrier(0);                                          \
} while (0)

#define RDA(OR, m) do {                                                         \
    i32x4 lo = *(const i32x4*)(lds + (OR) + wrA + (m) * 2048 + fo0);            \
    i32x4 hi = *(const i32x4*)(lds + (OR) + wrA + (m) * 2048 + fo1);            \
    fa[m] = __builtin_shufflevector(lo, hi, 0,1,2,3,4,5,6,7);                   \
    __builtin_amdgcn_sched_barrier(0);                                          \
} while (0)

#define RDB(OR) do {                                                            \
    _Pragma("unroll") for (int n = 0; n < 2; ++n) {                             \
        i32x4 lo = *(const i32x4*)(lds + (OR) + wcB + n * 2048 + fo0);          \
        i32x4 hi = *(const i32x4*)(lds + (OR) + wcB + n * 2048 + fo1);          \
        fb[n] = __builtin_shufflevector(lo, hi, 0,1,2,3,4,5,6,7);               \
    }                                                                           \
    __builtin_amdgcn_sched_barrier(0);                                          \
} while (0)

// iter t: stage tile t+2 -> buf OS; VM4 drains tile t+1; barrier;
// MFMA tile t interleaved with frag reads of tile t+1 from buf OR.
#define ITER(STG, VMW, OR, OS) do {                                             \
    if (STG) {                                                                  \
        stage_half(pA  + kt2, lds + (OS) + 0     + wave * 1024);                \
        stage_half(pAh + kt2, lds + (OS) + 8192  + wave * 1024);                \
        stage_half(pB  + kt2, lds + (OS) + 16384 + wave * 1024);                \
        stage_half(pBh + kt2, lds + (OS) + 24576 + wave * 1024);                \
        kt2 += 64;                                                              \
    }                                                                           \
    VMW;                                                                        \
    __builtin_amdgcn_s_barrier();                                               \
    MM2(0); RDA(OR, 0);                                                         \
    MM2(1); RDA(OR, 1);                                                         \
    MM2(2); RDA(OR, 2);                                                         \
    MM2(3); RDA(OR, 3); RDB(OR);                                                \
    LGKM0;                                                                      \
} while (0)

__global__ __launch_bounds__(512, 2) void gemm_fp8_kernel(
    const unsigned char* __restrict__ A,
    const unsigned char* __restrict__ B,
    float* __restrict__ C,
    const float* __restrict__ s_in,
    const float* __restrict__ s_w)
{
    __shared__ unsigned char lds[98304];   // 3 bufs x (A 16K + B 16K)

    const float alpha = s_in[0] * s_w[0];

    // XCD-bijective swizzle (512 blocks = 64/XCD) + 8x8 supertile per XCD
    const int b = blockIdx.x;
    const int local = b >> 3, chunk = b & 7;         // chunk = XCD id
    const int bm = (chunk & 3) * 8 + (local & 7);    // M/256 = 32
    const int bn = (chunk >> 2) * 8 + (local >> 3);  // N/256 = 16

    const int tid  = threadIdx.x;
    const int wave = tid >> 6;
    const int lane = tid & 63;
    const int wr   = wave >> 2;   // 2 M-waves
    const int wc   = wave & 3;    // 4 N-waves

    // frag ds_read: row = (lane&31), slot = (lane>>5)*2 + h, stored^((row>>1)&3)
    const int sw  = (lane >> 1) & 3;
    const int fo0 = (lane & 31) * 64 + ((((lane >> 5) * 2) + 0 ^ sw)) * 16;
    const int fo1 = (lane & 31) * 64 + ((((lane >> 5) * 2) + 1 ^ sw)) * 16;
    const int wrA = wr * 8192;            // A region: 128 rows per wr
    const int wcB = 16384 + wc * 4096;    // B region: 64 rows per wc

    // staging: thread tid covers LDS [row=tid>>2][slot=tid&3]; global slot XOR'd
    const int trow  = tid >> 2;
    const int tslot = (tid & 3) ^ ((tid >> 3) & 3);
    const unsigned char* pA  = A + (size_t)(bm * 256 + trow) * H_DIM + tslot * 16;
    const unsigned char* pAh = pA + (size_t)128 * H_DIM;
    const unsigned char* pB  = B + (size_t)(bn * 256 + trow) * H_DIM + tslot * 16;
    const unsigned char* pBh = pB + (size_t)128 * H_DIM;

    f32x16 acc[4][2];
#pragma unroll
    for (int m = 0; m < 4; ++m)
#pragma unroll
        for (int n = 0; n < 2; ++n)
#pragma unroll
            for (int e = 0; e < 16; ++e) acc[m][n][e] = 0.0f;

    i32x8 fa[4], fb[2];
    int kt2;

    // prologue: tile0 -> buf0, tile1 -> buf1; drain tile0; read tile0 frags
    stage_half(pA,       lds + 0     + wave * 1024);
    stage_half(pAh,      lds + 8192  + wave * 1024);
    stage_half(pB,       lds + 16384 + wave * 1024);
    stage_half(pBh,      lds + 24576 + wave * 1024);
    stage_half(pA  + 64, lds + 32768 + 0     + wave * 1024);
    stage_half(pAh + 64, lds + 32768 + 8192  + wave * 1024);
    stage_half(pB  + 64, lds + 32768 + 16384 + wave * 1024);
    stage_half(pBh + 64, lds + 32768 + 24576 + wave * 1024);
    VM4;
    __builtin_amdgcn_s_barrier();
    RDA(0, 0); RDA(0, 1); RDA(0, 2); RDA(0, 3); RDB(0);
    LGKM0;
    kt2 = 128;   // next stage target: tile 2, byte offset 2*64

    // 64 k-tiles; tile k lives in buf (k mod 3); at iter t: OR=buf((t+1)%3)
#pragma unroll 1
    for (int t3 = 0; t3 < 60; t3 += 3) {
        ITER(1, VM4, 32768, 65536);
        ITER(1, VM4, 65536, 0);
        ITER(1, VM4, 0,     32768);
    }
    ITER(1, VM4, 32768, 65536);   // t=60 (stages tile 62)
    ITER(1, VM4, 65536, 0);       // t=61 (stages tile 63 -> buf0)
    ITER(0, VM0, 0,     0);       // t=62 (drain tile 63; read its frags)
    MM2(0); MM2(1); MM2(2); MM2(3);   // t=63

    // epilogue: C += acc*alpha
    // (32x32 C/D: col = lane&31, row = (e&3) + 8*(e>>2) + 4*(lane>>5))
    const int lrow0 = bm * 256 + wr * 128 + 4 * (lane >> 5);
    const int lcol0 = bn * 256 + wc * 64 + (lane & 31);
#pragma unroll
    for (int m = 0; m < 4; ++m) {
#pragma unroll
        for (int n = 0; n < 2; ++n) {
#pragma unroll
            for (int e = 0; e < 16; ++e) {
                const int row = lrow0 + m * 32 + (e & 3) + 8 * (e >> 2);
                float* cp = C + (size_t)row * H_DIM + lcol0 + n * 32;
                *cp = acc[m][n][e] * alpha + *cp;
            }
        }
    }
}

extern "C" void kernel_launch(void* const* d_in, const int* in_sizes, int n_in,
                              void* d_out, int out_size, void* d_ws, size_t ws_size,
                              hipStream_t stream) {
    const float* h   = (const float*)d_in[0];   // [8192,4096]
    const float* nw  = (const float*)d_in[1];   // [4,4096]
    const float* w   = (const float*)d_in[2];   // [3,4096,4096]
    const float* wsc = (const float*)d_in[3];   // [3]
    const float* sc  = (const float*)d_in[4];   // [3]
    float* out = (float*)d_out;

    unsigned char* wqT = (unsigned char*)d_ws;                       // 3*16M fp8
    unsigned char* qx  = wqT + (size_t)3 * H_DIM * H_DIM;            // 33.5M fp8
    float* resid = (float*)(qx + (size_t)T_DIM * H_DIM);             // 134M f32

    const size_t WSTRIDE = (size_t)H_DIM * H_DIM;

    wquant_kernel<<<dim3(64, 64, 3), 256, 0, stream>>>(w, wqT);

    row_kernel<0><<<T_DIM, 256, 0, stream>>>(h, resid, qx, nw + 0 * H_DIM, sc + 0);
    gemm_fp8_kernel<<<512, 512, 0, stream>>>(qx, wqT + 0 * WSTRIDE, resid, sc + 0, wsc + 0);

    row_kernel<1><<<T_DIM, 256, 0, stream>>>(resid, nullptr, qx, nw + 1 * H_DIM, sc + 1);
    gemm_fp8_kernel<<<512, 512, 0, stream>>>(qx, wqT + 1 * WSTRIDE, resid, sc + 1, wsc + 1);

    row_kernel<1><<<T_DIM, 256, 0, stream>>>(resid, nullptr, qx, nw + 2 * H_DIM, sc + 2);
    gemm_fp8_kernel<<<512, 512, 0, stream>>>(qx, wqT + 2 * WSTRIDE, resid, sc + 2, wsc + 2);

    row_kernel<2><<<T_DIM, 256, 0, stream>>>(resid, nullptr, out, nw + 3 * H_DIM, nullptr);
}

// Round 6
// 646.984 us; speedup vs baseline: 2.5676x; 2.5676x over previous
//
#include <hip/hip_runtime.h>

typedef float f32x4  __attribute__((ext_vector_type(4)));
typedef float f32x16 __attribute__((ext_vector_type(16)));
typedef int   i32x4  __attribute__((ext_vector_type(4)));
typedef int   i32x8  __attribute__((ext_vector_type(8)));

#define T_DIM 8192
#define H_DIM 4096
#define SC1 0x7f7f7f7f   // e8m0 scale = 127 -> 2^0 = 1.0 in all 4 bytes

__device__ __forceinline__ unsigned int pack_fp8x4(float a, float b, float c, float d) {
    int v = __builtin_amdgcn_cvt_pk_fp8_f32(a, b, 0, false);
    v = __builtin_amdgcn_cvt_pk_fp8_f32(c, d, v, true);
    return (unsigned int)v;
}

// ---------------------------------------------------------------------------
// Global fp8 layout: PLAIN row-major [row][k] for both qx and wqT.
// (mfma_scale 32x32x64 frag = 32 CONTIGUOUS k-bytes per lane.)  Staging
// applies XOR slot swizzle slot' = slot ^ ((row>>1)&3) on the GLOBAL source
// addr (LDS stays linear for global_load_lds); ds_read applies the same XOR
// -> uniform 8 lanes per (parity,slot) bank-group = conflict-free b128.
// ---------------------------------------------------------------------------

// w[l][k][n] f32  ->  wqT[l][n][k] fp8(e4m3), plain layout
__global__ __launch_bounds__(256) void wquant_kernel(
    const float* __restrict__ w, unsigned char* __restrict__ wqT)
{
    const int l  = blockIdx.z;
    const int n0 = blockIdx.x * 64;
    const int k0 = blockIdx.y * 64;
    const int tid = threadIdx.x;
    __shared__ unsigned char tile[64][68];   // [k][n]
    const float* wl = w + (size_t)l * H_DIM * H_DIM;
#pragma unroll
    for (int p = 0; p < 4; ++p) {
        int r = p * 16 + (tid >> 4);         // k within tile
        int c = (tid & 15) * 4;              // n within tile
        f32x4 v = *(const f32x4*)(wl + (size_t)(k0 + r) * H_DIM + n0 + c);
        *(unsigned int*)&tile[r][c] = pack_fp8x4(v[0], v[1], v[2], v[3]);
    }
    __syncthreads();
    const int nl = tid >> 2;                 // n within tile (output row)
    const int g  = tid & 3;                  // 16B chunk within 64B
    unsigned int words[4];
#pragma unroll
    for (int wi = 0; wi < 4; ++wi) {
        unsigned int a = 0;
#pragma unroll
        for (int b = 0; b < 4; ++b)
            a |= (unsigned int)tile[g * 16 + wi * 4 + b][nl] << (8 * b);
        words[wi] = a;
    }
    unsigned char* op = wqT + ((size_t)l * H_DIM + n0 + nl) * H_DIM + k0 + g * 16;
    uint4 ov; ov.x = words[0]; ov.y = words[1]; ov.z = words[2]; ov.w = words[3];
    *(uint4*)op = ov;
}

// ---------------- row-wise RMSNorm (+relu) (+quant) ----------------
template <int MODE>
__global__ __launch_bounds__(256) void row_kernel(
    const float* __restrict__ in,
    float* __restrict__ resid_out,
    void* __restrict__ out,
    const float* __restrict__ g,
    const float* __restrict__ scale_p)
{
    const int row = blockIdx.x;
    const int tid = threadIdx.x;
    const float* rin = in + (size_t)row * H_DIM;
    float x[16];
    float ss = 0.0f;
#pragma unroll
    for (int j = 0; j < 4; ++j) {
        const int base = (j * 256 + tid) * 4;
        f32x4 v = *(const f32x4*)(rin + base);
        f32x4 rv;
#pragma unroll
        for (int i = 0; i < 4; ++i) {
            float t = v[i];
            if (MODE == 0) t = fmaxf(t, 0.0f);
            x[j * 4 + i] = t;
            rv[i] = t;
            ss += t * t;
        }
        if (MODE == 0)
            *(f32x4*)(resid_out + (size_t)row * H_DIM + base) = rv;
    }
#pragma unroll
    for (int off = 32; off > 0; off >>= 1)
        ss += __shfl_down(ss, off, 64);
    __shared__ float red[4];
    if ((tid & 63) == 0) red[tid >> 6] = ss;
    __syncthreads();
    const float var  = (red[0] + red[1] + red[2] + red[3]) * (1.0f / (float)H_DIM);
    const float rinv = 1.0f / sqrtf(var + 1e-6f);

    if (MODE == 2) {
        float* ro = (float*)out + (size_t)row * H_DIM;
#pragma unroll
        for (int j = 0; j < 4; ++j) {
            const int base = (j * 256 + tid) * 4;
            f32x4 gv = *(const f32x4*)(g + base);
            f32x4 ov;
#pragma unroll
            for (int i = 0; i < 4; ++i) ov[i] = (x[j * 4 + i] * rinv) * gv[i];
            *(f32x4*)(ro + base) = ov;
        }
    } else {
        const float s = scale_p[0];
        unsigned int* qo = (unsigned int*)out + (size_t)row * (H_DIM / 4);
#pragma unroll
        for (int j = 0; j < 4; ++j) {
            const int base = (j * 256 + tid) * 4;
            f32x4 gv = *(const f32x4*)(g + base);
            float q[4];
#pragma unroll
            for (int i = 0; i < 4; ++i) {
                float y = (x[j * 4 + i] * rinv) * gv[i];
                y = y / s;
                q[i] = fminf(fmaxf(y, -448.0f), 448.0f);
            }
            qo[j * 256 + tid] = pack_fp8x4(q[0], q[1], q[2], q[3]);
        }
    }
}

// ------- MX-fp8 GEMM, 256x256 tile, BK=64, 1 barrier/tile, 3-deep pipeline ---
// Half-grain interleave of MFMA (tile t) with ds_reads (tile t+1); no pins,
// compiler inserts counted lgkmcnt; sched_group_barrier nudges the emission
// order MFMA4/DS4/MFMA4/DS8.
__device__ __forceinline__ void stage_half(const unsigned char* gsrc, unsigned char* ldsdst) {
    __builtin_amdgcn_global_load_lds(
        (const __attribute__((address_space(1))) unsigned int*)gsrc,
        (__attribute__((address_space(3))) unsigned int*)ldsdst, 16, 0, 0);
}

#define VM4 asm volatile("s_waitcnt vmcnt(4)" ::: "memory")
#define VM0 asm volatile("s_waitcnt vmcnt(0)" ::: "memory")

#define MM2(m) do {                                                             \
    acc[m][0] = __builtin_amdgcn_mfma_scale_f32_32x32x64_f8f6f4(                \
        fa[m], fb[0], acc[m][0], 0, 0, 0, SC1, 0, SC1);                         \
    acc[m][1] = __builtin_amdgcn_mfma_scale_f32_32x32x64_f8f6f4(                \
        fa[m], fb[1], acc[m][1], 0, 0, 0, SC1, 0, SC1);                         \
} while (0)

#define RDA(OR, m) do {                                                         \
    *(i32x4*)&fa[m]        = *(const i32x4*)(lds + (OR) + wrA + (m) * 2048 + fo0); \
    *(((i32x4*)&fa[m]) + 1) = *(const i32x4*)(lds + (OR) + wrA + (m) * 2048 + fo1); \
} while (0)

#define RDB(OR) do {                                                            \
    _Pragma("unroll") for (int n = 0; n < 2; ++n) {                             \
        *(i32x4*)&fb[n]        = *(const i32x4*)(lds + (OR) + wcB + n * 2048 + fo0); \
        *(((i32x4*)&fb[n]) + 1) = *(const i32x4*)(lds + (OR) + wcB + n * 2048 + fo1); \
    }                                                                           \
} while (0)

// iter t: stage tile t+2 -> buf OS; VM4 drains tile t+1; barrier;
// MFMA tile t interleaved (half-grain) with frag reads of tile t+1 from OR.
#define ITER(STG, VMW, OR, OS) do {                                             \
    if (STG) {                                                                  \
        stage_half(bA  + (kt2 + voff), lds + (OS) + 0     + wave * 1024);       \
        stage_half(bAh + (kt2 + voff), lds + (OS) + 8192  + wave * 1024);       \
        stage_half(bB  + (kt2 + voff), lds + (OS) + 16384 + wave * 1024);       \
        stage_half(bBh + (kt2 + voff), lds + (OS) + 24576 + wave * 1024);       \
        kt2 += 64;                                                              \
    }                                                                           \
    VMW;                                                                        \
    __builtin_amdgcn_s_barrier();                                               \
    MM2(0); MM2(1);                                                             \
    RDA(OR, 0); RDA(OR, 1);                                                     \
    MM2(2); MM2(3);                                                             \
    RDA(OR, 2); RDA(OR, 3); RDB(OR);                                            \
    __builtin_amdgcn_sched_group_barrier(0x008, 4, 0);                          \
    __builtin_amdgcn_sched_group_barrier(0x100, 4, 0);                          \
    __builtin_amdgcn_sched_group_barrier(0x008, 4, 0);                          \
    __builtin_amdgcn_sched_group_barrier(0x100, 8, 0);                          \
} while (0)

__global__ __launch_bounds__(512, 2) void gemm_fp8_kernel(
    const unsigned char* __restrict__ A,
    const unsigned char* __restrict__ B,
    float* __restrict__ C,
    const float* __restrict__ s_in,
    const float* __restrict__ s_w)
{
    __shared__ unsigned char lds[98304];   // 3 bufs x (A 16K + B 16K)

    const float alpha = s_in[0] * s_w[0];

    // XCD-bijective swizzle (512 blocks = 64/XCD) + 8x8 supertile per XCD
    const int b = blockIdx.x;
    const int local = b >> 3, chunk = b & 7;         // chunk = XCD id
    const int bm = (chunk & 3) * 8 + (local & 7);    // M/256 = 32
    const int bn = (chunk >> 2) * 8 + (local >> 3);  // N/256 = 16

    const int tid  = threadIdx.x;
    const int wave = tid >> 6;
    const int lane = tid & 63;
    const int wr   = wave >> 2;   // 2 M-waves
    const int wc   = wave & 3;    // 4 N-waves

    // frag ds_read: row = (lane&31), slot = (lane>>5)*2 + h, stored^((row>>1)&3)
    const int sw  = (lane >> 1) & 3;
    const int fo0 = (lane & 31) * 64 + ((((lane >> 5) * 2) + 0 ^ sw)) * 16;
    const int fo1 = (lane & 31) * 64 + ((((lane >> 5) * 2) + 1 ^ sw)) * 16;
    const int wrA = wr * 8192;            // A region: 128 rows per wr
    const int wcB = 16384 + wc * 4096;    // B region: 64 rows per wc

    // staging: uniform SGPR bases + one shared per-thread 32-bit voffset
    // (thread tid covers LDS [row=tid>>2][slot=tid&3]; global slot XOR'd)
    const int voff = (tid >> 2) * H_DIM + ((tid & 3) ^ ((tid >> 3) & 3)) * 16;
    const unsigned char* bA  = A + (size_t)bm * 256 * H_DIM;
    const unsigned char* bAh = bA + (size_t)128 * H_DIM;
    const unsigned char* bB  = B + (size_t)bn * 256 * H_DIM;
    const unsigned char* bBh = bB + (size_t)128 * H_DIM;

    f32x16 acc[4][2];
#pragma unroll
    for (int m = 0; m < 4; ++m)
#pragma unroll
        for (int n = 0; n < 2; ++n)
#pragma unroll
            for (int e = 0; e < 16; ++e) acc[m][n][e] = 0.0f;

    i32x8 fa[4], fb[2];
    int kt2;

    // prologue: tile0 -> buf0, tile1 -> buf1; drain tile0; read tile0 frags
    stage_half(bA  + voff, lds + 0     + wave * 1024);
    stage_half(bAh + voff, lds + 8192  + wave * 1024);
    stage_half(bB  + voff, lds + 16384 + wave * 1024);
    stage_half(bBh + voff, lds + 24576 + wave * 1024);
    stage_half(bA  + (voff + 64), lds + 32768 + 0     + wave * 1024);
    stage_half(bAh + (voff + 64), lds + 32768 + 8192  + wave * 1024);
    stage_half(bB  + (voff + 64), lds + 32768 + 16384 + wave * 1024);
    stage_half(bBh + (voff + 64), lds + 32768 + 24576 + wave * 1024);
    VM4;
    __builtin_amdgcn_s_barrier();
    RDA(0, 0); RDA(0, 1); RDA(0, 2); RDA(0, 3); RDB(0);
    kt2 = 128;   // next stage target: tile 2

    // 64 k-tiles; tile k lives in buf (k mod 3); at iter t: OR = buf((t+1)%3)
#pragma unroll 1
    for (int t3 = 0; t3 < 60; t3 += 3) {
        ITER(1, VM4, 32768, 65536);
        ITER(1, VM4, 65536, 0);
        ITER(1, VM4, 0,     32768);
    }
    ITER(1, VM4, 32768, 65536);   // t=60 (stages tile 62)
    ITER(1, VM4, 65536, 0);       // t=61 (stages tile 63 -> buf0)
    ITER(0, VM0, 0,     0);       // t=62 (drain tile 63; read its frags)
    MM2(0); MM2(1); MM2(2); MM2(3);   // t=63

    // epilogue: C += acc*alpha
    // (32x32 C/D: col = lane&31, row = (e&3) + 8*(e>>2) + 4*(lane>>5))
    const int lrow0 = bm * 256 + wr * 128 + 4 * (lane >> 5);
    const int lcol0 = bn * 256 + wc * 64 + (lane & 31);
#pragma unroll
    for (int m = 0; m < 4; ++m) {
#pragma unroll
        for (int n = 0; n < 2; ++n) {
#pragma unroll
            for (int e = 0; e < 16; ++e) {
                const int row = lrow0 + m * 32 + (e & 3) + 8 * (e >> 2);
                float* cp = C + (size_t)row * H_DIM + lcol0 + n * 32;
                *cp = acc[m][n][e] * alpha + *cp;
            }
        }
    }
}

extern "C" void kernel_launch(void* const* d_in, const int* in_sizes, int n_in,
                              void* d_out, int out_size, void* d_ws, size_t ws_size,
                              hipStream_t stream) {
    const float* h   = (const float*)d_in[0];   // [8192,4096]
    const float* nw  = (const float*)d_in[1];   // [4,4096]
    const float* w   = (const float*)d_in[2];   // [3,4096,4096]
    const float* wsc = (const float*)d_in[3];   // [3]
    const float* sc  = (const float*)d_in[4];   // [3]
    float* out = (float*)d_out;

    unsigned char* wqT = (unsigned char*)d_ws;                       // 3*16M fp8
    unsigned char* qx  = wqT + (size_t)3 * H_DIM * H_DIM;            // 33.5M fp8
    float* resid = (float*)(qx + (size_t)T_DIM * H_DIM);             // 134M f32

    const size_t WSTRIDE = (size_t)H_DIM * H_DIM;

    wquant_kernel<<<dim3(64, 64, 3), 256, 0, stream>>>(w, wqT);

    row_kernel<0><<<T_DIM, 256, 0, stream>>>(h, resid, qx, nw + 0 * H_DIM, sc + 0);
    gemm_fp8_kernel<<<512, 512, 0, stream>>>(qx, wqT + 0 * WSTRIDE, resid, sc + 0, wsc + 0);

    row_kernel<1><<<T_DIM, 256, 0, stream>>>(resid, nullptr, qx, nw + 1 * H_DIM, sc + 1);
    gemm_fp8_kernel<<<512, 512, 0, stream>>>(qx, wqT + 1 * WSTRIDE, resid, sc + 1, wsc + 1);

    row_kernel<1><<<T_DIM, 256, 0, stream>>>(resid, nullptr, qx, nw + 2 * H_DIM, sc + 2);
    gemm_fp8_kernel<<<512, 512, 0, stream>>>(qx, wqT + 2 * WSTRIDE, resid, sc + 2, wsc + 2);

    row_kernel<2><<<T_DIM, 256, 0, stream>>>(resid, nullptr, out, nw + 3 * H_DIM, nullptr);
}